// Round 1
// baseline (2777.672 us; speedup 1.0000x reference)
//
#include <hip/hip_runtime.h>
#include <hip/hip_bf16.h>

#define NN 50000
#define EE 800000
#define TT 3
#define ED 64
#define NS 23
#define MD 87
#define HH 200
#define NMOL 2048
#define RD 256

// ---------------- setup kernels ----------------

__global__ __launch_bounds__(256) void emb_kernel(const int* __restrict__ z,
                                                  const float* __restrict__ emb,
                                                  float* __restrict__ x_all) {
  int idx = blockIdx.x * 256 + threadIdx.x;  // over N*64
  if (idx >= NN * ED) return;
  int i = idx >> 6, d = idx & 63;
  x_all[i * RD + d] = emb[z[i] * ED + d];
}

__global__ __launch_bounds__(256) void hist_kernel(const int* __restrict__ src,
                                                   int* __restrict__ deg) {
  int e = blockIdx.x * 256 + threadIdx.x;
  if (e < EE) atomicAdd(&deg[src[e]], 1);
}

__global__ __launch_bounds__(1024) void scan_kernel(const int* __restrict__ deg,
                                                    int* __restrict__ offs,
                                                    int* __restrict__ cursor, int n) {
  __shared__ int sh[1024];
  __shared__ int carry_sh;
  int tid = threadIdx.x;
  if (tid == 0) carry_sh = 0;
  __syncthreads();
  for (int base = 0; base < n; base += 1024) {
    int i = base + tid;
    int v = (i < n) ? deg[i] : 0;
    sh[tid] = v;
    __syncthreads();
    for (int off = 1; off < 1024; off <<= 1) {
      int t = (tid >= off) ? sh[tid - off] : 0;
      __syncthreads();
      sh[tid] += t;
      __syncthreads();
    }
    int carry = carry_sh;
    int excl = carry + sh[tid] - v;
    if (i < n) { offs[i] = excl; cursor[i] = excl; }
    __syncthreads();
    if (tid == 0) carry_sh = carry + sh[1023];
    __syncthreads();
  }
  if (tid == 0) offs[n] = carry_sh;
}

__global__ __launch_bounds__(256) void scatter_kernel(const int* __restrict__ src,
                                                      const int* __restrict__ snk,
                                                      const float* __restrict__ dist,
                                                      int* __restrict__ cursor,
                                                      int* __restrict__ ssink,
                                                      float* __restrict__ sdist) {
  int e = blockIdx.x * 256 + threadIdx.x;
  if (e >= EE) return;
  int p = atomicAdd(&cursor[src[e]], 1);
  ssink[p] = snk[e];
  sdist[p] = dist[e];
}

// ---------------- message gather (segment_sum via CSR) ----------------
// one wave per node: lane d accumulates sum over edges of x[sink][d];
// lanes < 23 also recompute rbf = exp(-(d - shift)^2) on the fly.

__global__ __launch_bounds__(256) void gather_kernel(const int* __restrict__ offs,
                                                     const int* __restrict__ ssink,
                                                     const float* __restrict__ sdist,
                                                     const float* __restrict__ x_all,
                                                     int toff, float* __restrict__ m) {
  int node = blockIdx.x * 4 + (threadIdx.x >> 6);
  int lane = threadIdx.x & 63;
  if (node >= NN) return;
  float shift = (float)(0.8 + 0.1 * (double)lane);
  float accx = 0.f, accr = 0.f;
  int e0 = offs[node], e1 = offs[node + 1];
  for (int j = e0; j < e1; ++j) {
    int s = ssink[j];
    accx += x_all[s * RD + toff + lane];
    if (lane < NS) {
      float u = sdist[j] - shift;
      accr += __expf(-u * u);
    }
  }
  if (lane < NS) m[node * MD + lane] = accr;
  m[node * MD + NS + lane] = accx;
}

// ---------------- batchnorm stats (2-stage, no atomics/memset) ----------------

__global__ __launch_bounds__(256) void colstats_kernel(const float* __restrict__ X, int ld,
                                                       int ncols, float* __restrict__ P) {
  int c = threadIdx.x;
  float s = 0.f, q = 0.f;
  if (c < ncols) {
    for (int r = blockIdx.x; r < NN; r += gridDim.x) {
      float v = X[(long long)r * ld + c];
      s += v;
      q += v * v;
    }
  }
  P[blockIdx.x * 512 + c] = s;
  P[blockIdx.x * 512 + 256 + c] = q;
}

__global__ __launch_bounds__(256) void bnfinal_kernel(const float* __restrict__ P, int nblk,
                                                      const float* __restrict__ g,
                                                      const float* __restrict__ b, int ncols,
                                                      float* __restrict__ na,
                                                      float* __restrict__ nb) {
  int c = threadIdx.x;
  if (c >= ncols) return;
  float s = 0.f, q = 0.f;
  for (int i = 0; i < nblk; i++) {
    s += P[i * 512 + c];
    q += P[i * 512 + 256 + c];
  }
  float mean = s / (float)NN;
  float var = q / (float)NN - mean * mean;
  float a = g[c] * rsqrtf(var + 1e-5f);
  na[c] = a;
  nb[c] = b[c] - mean * a;
}

// ---------------- fp32 GEMM: 128x128 tile, 8x8 micro, BN folded into A-load ----
// EPI 0: C = relu(acc + bias)
// EPI 1: C = R + 0.1*(acc + bias)

template <int EPI, bool NORM>
__global__ __launch_bounds__(256) void gemm128(const float* __restrict__ A, int lda,
                                               const float* __restrict__ B, int ldb,
                                               const float* __restrict__ bias,
                                               const float* __restrict__ na,
                                               const float* __restrict__ nb,
                                               const float* __restrict__ R, int ldr,
                                               float* __restrict__ C, int ldc,
                                               int M, int K, int Nn) {
  __shared__ float As[16][128];
  __shared__ float Bs[16][128];
  const int tid = threadIdx.x;
  const int tx = tid & 15, ty = tid >> 4;
  const int bm = blockIdx.x * 128, bn = blockIdx.y * 128;
  float acc[8][8];
#pragma unroll
  for (int i = 0; i < 8; i++)
#pragma unroll
    for (int j = 0; j < 8; j++) acc[i][j] = 0.f;

  const int am = tid >> 1;        // 0..127
  const int ak = (tid & 1) * 8;   // 0 / 8
  const int bk = tid >> 4;        // 0..15
  const int bnn = (tid & 15) * 8; // 0..120
  const bool mok = (bm + am) < M;

  for (int k0 = 0; k0 < K; k0 += 16) {
    const float* Ap = A + (long long)(bm + am) * lda + (k0 + ak);
#pragma unroll
    for (int i = 0; i < 8; i++) {
      int kg = k0 + ak + i;
      float v = 0.f;
      if (mok && kg < K) {
        v = Ap[i];
        if (NORM) v = v * na[kg] + nb[kg];
      }
      As[ak + i][am] = v;
    }
    const float* Bp = B + (long long)(k0 + bk) * ldb + bn + bnn;
    const bool kok = (k0 + bk) < K;
#pragma unroll
    for (int j = 0; j < 8; j++) {
      int ng = bn + bnn + j;
      Bs[bk][bnn + j] = (kok && ng < Nn) ? Bp[j] : 0.f;
    }
    __syncthreads();
#pragma unroll
    for (int k = 0; k < 16; k++) {
      float4 a0 = *(const float4*)&As[k][ty * 8];
      float4 a1 = *(const float4*)&As[k][ty * 8 + 4];
      float4 b0 = *(const float4*)&Bs[k][tx * 8];
      float4 b1 = *(const float4*)&Bs[k][tx * 8 + 4];
      float av[8] = {a0.x, a0.y, a0.z, a0.w, a1.x, a1.y, a1.z, a1.w};
      float bv[8] = {b0.x, b0.y, b0.z, b0.w, b1.x, b1.y, b1.z, b1.w};
#pragma unroll
      for (int i = 0; i < 8; i++)
#pragma unroll
        for (int j = 0; j < 8; j++) acc[i][j] = fmaf(av[i], bv[j], acc[i][j]);
    }
    __syncthreads();
  }

#pragma unroll
  for (int i = 0; i < 8; i++) {
    int r = bm + ty * 8 + i;
    if (r >= M) continue;
#pragma unroll
    for (int j = 0; j < 8; j++) {
      int c = bn + tx * 8 + j;
      if (c >= Nn) continue;
      float v = acc[i][j] + bias[c];
      if (EPI == 0) {
        v = v > 0.f ? v : 0.f;
      } else {
        v = R[(long long)r * ldr + c] + 0.1f * v;
      }
      C[(long long)r * ldc + c] = v;
    }
  }
}

// ---------------- fused final layer (200->1) + molecule segment-sum ----------

__global__ __launch_bounds__(256) void final_kernel(const float* __restrict__ h,
                                                    const float* __restrict__ w4,
                                                    const float* __restrict__ b4,
                                                    const int* __restrict__ mol,
                                                    float* __restrict__ out) {
  int node = blockIdx.x * 4 + (threadIdx.x >> 6);
  int lane = threadIdx.x & 63;
  if (node >= NN) return;
  float s = 0.f;
  for (int c = lane; c < HH; c += 64) s += h[node * HH + c] * w4[c];
  for (int off = 32; off > 0; off >>= 1) s += __shfl_down(s, off, 64);
  if (lane == 0) atomicAdd(&out[mol[node]], s + b4[0]);
}

// ---------------- host launcher ----------------

extern "C" void kernel_launch(void* const* d_in, const int* in_sizes, int n_in,
                              void* d_out, int out_size, void* d_ws, size_t ws_size,
                              hipStream_t stream) {
  const int* z_i = (const int*)d_in[0];
  const int* e_src = (const int*)d_in[1];
  const int* e_snk = ((const int*)d_in[1]) + EE;
  const float* dist = (const float*)d_in[2];
  const int* mol = (const int*)d_in[3];
  const float* emb = (const float*)d_in[4];
  const float* up_bn_g = (const float*)d_in[5];
  const float* up_bn_b = (const float*)d_in[6];
  const float* up_w1 = (const float*)d_in[7];
  const float* up_b1 = (const float*)d_in[8];
  const float* up_w2 = (const float*)d_in[9];
  const float* up_b2 = (const float*)d_in[10];
  const float* up_w3 = (const float*)d_in[11];
  const float* up_b3 = (const float*)d_in[12];
  const float* up_w4 = (const float*)d_in[13];
  const float* up_b4 = (const float*)d_in[14];
  const float* ro_bn_g = (const float*)d_in[15];
  const float* ro_bn_b = (const float*)d_in[16];
  const float* ro_w1 = (const float*)d_in[17];
  const float* ro_b1 = (const float*)d_in[18];
  const float* ro_w2 = (const float*)d_in[19];
  const float* ro_b2 = (const float*)d_in[20];
  const float* ro_w3 = (const float*)d_in[21];
  const float* ro_b3 = (const float*)d_in[22];
  const float* ro_w4 = (const float*)d_in[23];
  const float* ro_b4 = (const float*)d_in[24];
  float* out = (float*)d_out;

  char* p = (char*)d_ws;
  auto alloc = [&](size_t bytes) {
    void* r = (void*)p;
    p += (bytes + 255) & ~(size_t)255;
    return r;
  };
  float* x_all = (float*)alloc((size_t)NN * RD * 4);
  float* m = (float*)alloc((size_t)NN * MD * 4);
  float* h1 = (float*)alloc((size_t)NN * HH * 4);
  float* h2 = (float*)alloc((size_t)NN * HH * 4);
  int* ssink = (int*)alloc((size_t)EE * 4);
  float* sdist = (float*)alloc((size_t)EE * 4);
  int* deg = (int*)alloc((size_t)NN * 4);
  int* offs = (int*)alloc((size_t)(NN + 1) * 4);
  int* cursor = (int*)alloc((size_t)NN * 4);
  float* P = (float*)alloc((size_t)200 * 512 * 4);
  float* na = (float*)alloc(256 * 4);
  float* nb = (float*)alloc(256 * 4);

  hipMemsetAsync(deg, 0, (size_t)NN * 4, stream);
  hipMemsetAsync(out, 0, (size_t)NMOL * 4, stream);

  emb_kernel<<<(NN * ED + 255) / 256, 256, 0, stream>>>(z_i, emb, x_all);
  hist_kernel<<<(EE + 255) / 256, 256, 0, stream>>>(e_src, deg);
  scan_kernel<<<1, 1024, 0, stream>>>(deg, offs, cursor, NN);
  scatter_kernel<<<(EE + 255) / 256, 256, 0, stream>>>(e_src, e_snk, dist, cursor, ssink, sdist);

  const int gM = (NN + 127) / 128;  // 391

  for (int t = 0; t < TT; t++) {
    gather_kernel<<<(NN + 3) / 4, 256, 0, stream>>>(offs, ssink, sdist, x_all, t * ED, m);
    colstats_kernel<<<200, 256, 0, stream>>>(m, MD, MD, P);
    bnfinal_kernel<<<1, 256, 0, stream>>>(P, 200, up_bn_g + t * MD, up_bn_b + t * MD, MD, na, nb);

    // L1: m[87] -> h1[200], BN folded, relu
    gemm128<0, true><<<dim3(gM, 2), 256, 0, stream>>>(
        m, MD, up_w1 + t * MD * HH, HH, up_b1 + t * HH, na, nb, nullptr, 0, h1, HH, NN, MD, HH);
    // L2: h1 -> h2, relu
    gemm128<0, false><<<dim3(gM, 2), 256, 0, stream>>>(
        h1, HH, up_w2 + t * HH * HH, HH, up_b2 + t * HH, na, nb, nullptr, 0, h2, HH, NN, HH, HH);
    // L3: h2 -> h1, relu
    gemm128<0, false><<<dim3(gM, 2), 256, 0, stream>>>(
        h2, HH, up_w3 + t * HH * HH, HH, up_b3 + t * HH, na, nb, nullptr, 0, h1, HH, NN, HH, HH);
    // L4: h1 -> x_all slice t+1 = x_all slice t + 0.1*(h1@W4+b4)
    gemm128<1, false><<<dim3(gM, 1), 256, 0, stream>>>(
        h1, HH, up_w4 + t * HH * ED, ED, up_b4 + t * ED, na, nb, x_all + t * ED, RD,
        x_all + (t + 1) * ED, RD, NN, HH, ED);
  }

  // readout
  colstats_kernel<<<200, 256, 0, stream>>>(x_all, RD, RD, P);
  bnfinal_kernel<<<1, 256, 0, stream>>>(P, 200, ro_bn_g, ro_bn_b, RD, na, nb);
  gemm128<0, true><<<dim3(gM, 2), 256, 0, stream>>>(
      x_all, RD, ro_w1, HH, ro_b1, na, nb, nullptr, 0, h1, HH, NN, RD, HH);
  gemm128<0, false><<<dim3(gM, 2), 256, 0, stream>>>(
      h1, HH, ro_w2, HH, ro_b2, na, nb, nullptr, 0, h2, HH, NN, HH, HH);
  gemm128<0, false><<<dim3(gM, 2), 256, 0, stream>>>(
      h2, HH, ro_w3, HH, ro_b3, na, nb, nullptr, 0, h1, HH, NN, HH, HH);
  final_kernel<<<(NN + 3) / 4, 256, 0, stream>>>(h1, ro_w4, ro_b4, mol, out);

  (void)in_sizes; (void)n_in; (void)out_size; (void)ws_size;
}

// Round 2
// 2489.524 us; speedup vs baseline: 1.1157x; 1.1157x over previous
//
#include <hip/hip_runtime.h>
#include <hip/hip_bf16.h>

#define NN 50000
#define EE 800000
#define TT 3
#define ED 64
#define NS 23
#define MD 87
#define HH 200
#define NMOL 2048
#define RD 256

typedef __attribute__((ext_vector_type(8))) short short8b;
typedef __attribute__((ext_vector_type(4))) float f32x4;

// ---- bf16 split helpers: value = hi + lo, each bf16 (RNE). ----
__device__ __forceinline__ unsigned short f2bf(float f) {
  unsigned u = __float_as_uint(f);
  return (unsigned short)((u + 0x7fffu + ((u >> 16) & 1u)) >> 16);
}
__device__ __forceinline__ float ubf2f(unsigned short h) {
  return __uint_as_float(((unsigned)h) << 16);
}
__device__ __forceinline__ void split2(float v, unsigned short& h, unsigned short& l) {
  h = f2bf(v);
  l = f2bf(v - ubf2f(h));
}
// interleaved pair: low16 = hi, high16 = lo
__device__ __forceinline__ float bfp2f(unsigned p) {
  return __uint_as_float(p << 16) + __uint_as_float(p & 0xffff0000u);
}
__device__ __forceinline__ unsigned packsplit(float v) {
  unsigned short h, l;
  split2(v, h, l);
  return (unsigned)h | ((unsigned)l << 16);
}

// ---------------- weight split: fp32 -> (hi, lo) bf16 arrays ----------------
__global__ __launch_bounds__(256) void wsplit_kernel(const float* __restrict__ src, int n,
                                                     short* __restrict__ dh,
                                                     short* __restrict__ dl) {
  int i = blockIdx.x * 256 + threadIdx.x;
  if (i >= n) return;
  unsigned short h, l;
  split2(src[i], h, l);
  dh[i] = (short)h;
  dl[i] = (short)l;
}

// ---------------- embedding -> x pair slice 0 ----------------
__global__ __launch_bounds__(256) void embsplit_kernel(const int* __restrict__ z,
                                                       const float* __restrict__ emb,
                                                       unsigned* __restrict__ xp) {
  int idx = blockIdx.x * 256 + threadIdx.x;
  if (idx >= NN * ED) return;
  int i = idx >> 6, d = idx & 63;
  xp[(size_t)i * RD + d] = packsplit(emb[z[i] * ED + d]);
}

// ---------------- CSR build ----------------
__global__ __launch_bounds__(256) void hist_kernel(const int* __restrict__ src,
                                                   int* __restrict__ deg) {
  int e = blockIdx.x * 256 + threadIdx.x;
  if (e < EE) atomicAdd(&deg[src[e]], 1);
}

__global__ __launch_bounds__(1024) void scan_kernel(const int* __restrict__ deg,
                                                    int* __restrict__ offs,
                                                    int* __restrict__ cursor) {
  __shared__ int sh[1024];
  int tid = threadIdx.x;
  const int CH = (NN + 1023) / 1024;  // 49
  int s0 = tid * CH, s1 = s0 + CH;
  if (s1 > NN) s1 = NN;
  int sum = 0;
  for (int i = s0; i < s1; i++) sum += deg[i];
  sh[tid] = sum;
  __syncthreads();
  for (int off = 1; off < 1024; off <<= 1) {
    int t = (tid >= off) ? sh[tid - off] : 0;
    __syncthreads();
    sh[tid] += t;
    __syncthreads();
  }
  int base = sh[tid] - sum;  // exclusive prefix
  for (int i = s0; i < s1; i++) {
    offs[i] = base;
    cursor[i] = base;
    base += deg[i];
  }
  if (tid == 1023) offs[NN] = sh[1023];
}

__global__ __launch_bounds__(256) void scatter_kernel(const int* __restrict__ src,
                                                      const int* __restrict__ snk,
                                                      const float* __restrict__ dist,
                                                      int* __restrict__ cursor,
                                                      int* __restrict__ ssink,
                                                      float* __restrict__ sdist) {
  int e = blockIdx.x * 256 + threadIdx.x;
  if (e >= EE) return;
  int p = atomicAdd(&cursor[src[e]], 1);
  ssink[p] = snk[e];
  sdist[p] = dist[e];
}

// ---------------- message gather: one wave per node, writes m pair ----------
__global__ __launch_bounds__(256) void gather_kernel(const int* __restrict__ offs,
                                                     const int* __restrict__ ssink,
                                                     const float* __restrict__ sdist,
                                                     const unsigned* __restrict__ xp,
                                                     int toff, short* __restrict__ mh,
                                                     short* __restrict__ ml) {
  int node = blockIdx.x * 4 + (threadIdx.x >> 6);
  int lane = threadIdx.x & 63;
  if (node >= NN) return;
  float shift = (float)(0.8 + 0.1 * (double)lane);
  float accx = 0.f, accr = 0.f;
  int e0 = offs[node], e1 = offs[node + 1];
  for (int j = e0; j < e1; ++j) {
    int s = ssink[j];
    accx += bfp2f(xp[(size_t)s * RD + toff + lane]);
    if (lane < NS) {
      float u = sdist[j] - shift;
      accr += __expf(-u * u);
    }
  }
  unsigned short h, l;
  if (lane < NS) {
    split2(accr, h, l);
    mh[node * 96 + lane] = (short)h;
    ml[node * 96 + lane] = (short)l;
  }
  split2(accx, h, l);
  mh[node * 96 + NS + lane] = (short)h;
  ml[node * 96 + NS + lane] = (short)l;
}

// ---------------- batchnorm stats ----------------
__global__ __launch_bounds__(256) void colstats_pair_kernel(const short* __restrict__ Xh,
                                                            const short* __restrict__ Xl,
                                                            int ld, int ncols,
                                                            float* __restrict__ P) {
  int c = threadIdx.x;
  float s = 0.f, q = 0.f;
  if (c < ncols) {
    for (int r = blockIdx.x; r < NN; r += gridDim.x) {
      float v = ubf2f((unsigned short)Xh[(size_t)r * ld + c]) +
                ubf2f((unsigned short)Xl[(size_t)r * ld + c]);
      s += v;
      q += v * v;
    }
  }
  P[blockIdx.x * 512 + c] = s;
  P[blockIdx.x * 512 + 256 + c] = q;
}

__global__ __launch_bounds__(256) void colstats_px_kernel(const unsigned* __restrict__ xp,
                                                          float* __restrict__ P) {
  int c = threadIdx.x;
  float s = 0.f, q = 0.f;
  for (int r = blockIdx.x; r < NN; r += gridDim.x) {
    float v = bfp2f(xp[(size_t)r * RD + c]);
    s += v;
    q += v * v;
  }
  P[blockIdx.x * 512 + c] = s;
  P[blockIdx.x * 512 + 256 + c] = q;
}

__global__ __launch_bounds__(256) void bnfinal_kernel(const float* __restrict__ P, int nblk,
                                                      const float* __restrict__ g,
                                                      const float* __restrict__ b, int ncols,
                                                      float* __restrict__ na,
                                                      float* __restrict__ nb) {
  int c = threadIdx.x;
  if (c >= ncols) return;
  float s = 0.f, q = 0.f;
  for (int i = 0; i < nblk; i++) {
    s += P[i * 512 + c];
    q += P[i * 512 + 256 + c];
  }
  float mean = s / (float)NN;
  float var = q / (float)NN - mean * mean;
  float a = g[c] * rsqrtf(var + 1e-5f);
  na[c] = a;
  nb[c] = b[c] - mean * a;
}

// in-place BN on m pair; zero pad cols [87,96)
__global__ __launch_bounds__(256) void bnsplit_m_kernel(short* __restrict__ mh,
                                                        short* __restrict__ ml,
                                                        const float* __restrict__ na,
                                                        const float* __restrict__ nb) {
  int idx = blockIdx.x * 256 + threadIdx.x;
  if (idx >= NN * 96) return;
  int c = idx % 96;
  if (c < MD) {
    float f = ubf2f((unsigned short)mh[idx]) + ubf2f((unsigned short)ml[idx]);
    f = f * na[c] + nb[c];
    unsigned short h, l;
    split2(f, h, l);
    mh[idx] = (short)h;
    ml[idx] = (short)l;
  } else {
    mh[idx] = 0;
    ml[idx] = 0;
  }
}

// ---------------- split-precision MFMA GEMM ----------------
// C[M x Nn] = act(A * B + bias), A as bf16 hi/lo pairs (fp32-equivalent),
// B (weights) as bf16 hi/lo pairs. 3 MFMA per tile: hh + hl + lh.
// Block tile 128x64, 4 waves (2x2), wave tile 64x32, K-step 32.
// EPI 0: relu, output split pair (Ch, Cl). EPI 1: xp[tw] = xp[tr] + 0.1*v.
// XNORM: A is interleaved x-pair with BN affine applied at staging.
template <int EPI, bool XNORM>
__global__ __launch_bounds__(256) void mgemm(
    const short* __restrict__ Ah, const short* __restrict__ Al,
    const unsigned* __restrict__ Ax, int lda, const short* __restrict__ Bh,
    const short* __restrict__ Bl, int ldb, const float* __restrict__ bias,
    const float* __restrict__ na, const float* __restrict__ nb,
    unsigned* __restrict__ xp, int tr, int tw, short* __restrict__ Ch,
    short* __restrict__ Cl, int ldc, int M, int K, int KA, int KP, int Nn) {
  __shared__ short As_h[128 * 40];
  __shared__ short As_l[128 * 40];
  __shared__ short Bs_h[64 * 40];
  __shared__ short Bs_l[64 * 40];
  const int tid = threadIdx.x;
  const int bm = blockIdx.x * 128, bn = blockIdx.y * 64;
  const int wave = tid >> 6, lane = tid & 63, ln = lane & 15, quad = lane >> 4;
  const int wm = wave & 1, wn = wave >> 1;

  f32x4 acc[4][2];
#pragma unroll
  for (int i = 0; i < 4; i++)
#pragma unroll
    for (int j = 0; j < 2; j++) acc[i][j] = (f32x4){0.f, 0.f, 0.f, 0.f};

  const int arow = tid >> 1;          // 0..127
  const int ahalf = (tid & 1) * 16;   // 0 or 16
  const int bnn = tid & 63, bk0 = tid >> 6;  // n lane, k base 0..3
  const int arw = bm + arow;
  const bool rok = arw < M;
  const int ngl = bn + bnn;
  const bool nok = ngl < Nn;

  for (int k0 = 0; k0 < KP; k0 += 32) {
    // ---- A staging ----
    if (!XNORM) {
      if (k0 + 32 <= KA && rok) {
        const short* pa = Ah + (size_t)arw * lda + k0 + ahalf;
        const short* pb = Al + (size_t)arw * lda + k0 + ahalf;
        *(short8b*)&As_h[arow * 40 + ahalf] = *(const short8b*)pa;
        *(short8b*)&As_h[arow * 40 + ahalf + 8] = *(const short8b*)(pa + 8);
        *(short8b*)&As_l[arow * 40 + ahalf] = *(const short8b*)pb;
        *(short8b*)&As_l[arow * 40 + ahalf + 8] = *(const short8b*)(pb + 8);
      } else {
#pragma unroll
        for (int e = 0; e < 16; e++) {
          int kg = k0 + ahalf + e;
          short h = 0, l = 0;
          if (rok && kg < KA) {
            h = Ah[(size_t)arw * lda + kg];
            l = Al[(size_t)arw * lda + kg];
          }
          As_h[arow * 40 + ahalf + e] = h;
          As_l[arow * 40 + ahalf + e] = l;
        }
      }
    } else {
#pragma unroll
      for (int e = 0; e < 16; e++) {
        int kg = k0 + ahalf + e;
        float f = 0.f;
        if (rok) f = bfp2f(Ax[(size_t)arw * lda + kg]);
        f = f * na[kg] + nb[kg];
        unsigned short h, l;
        split2(f, h, l);
        As_h[arow * 40 + ahalf + e] = (short)h;
        As_l[arow * 40 + ahalf + e] = (short)l;
      }
    }
    // ---- B staging (transpose to [n][k]) ----
#pragma unroll
    for (int p = 0; p < 8; p++) {
      int kg = k0 + bk0 + p * 4;
      short h = 0, l = 0;
      if (nok && kg < K) {
        h = Bh[(size_t)kg * ldb + ngl];
        l = Bl[(size_t)kg * ldb + ngl];
      }
      Bs_h[bnn * 40 + bk0 + p * 4] = h;
      Bs_l[bnn * 40 + bk0 + p * 4] = l;
    }
    __syncthreads();
    short8b ah[4], al[4], bh[2], bl[2];
#pragma unroll
    for (int i = 0; i < 4; i++) {
      int r = wm * 64 + i * 16 + ln;
      ah[i] = *(const short8b*)&As_h[r * 40 + quad * 8];
      al[i] = *(const short8b*)&As_l[r * 40 + quad * 8];
    }
#pragma unroll
    for (int j = 0; j < 2; j++) {
      int r = wn * 32 + j * 16 + ln;
      bh[j] = *(const short8b*)&Bs_h[r * 40 + quad * 8];
      bl[j] = *(const short8b*)&Bs_l[r * 40 + quad * 8];
    }
#pragma unroll
    for (int i = 0; i < 4; i++)
#pragma unroll
      for (int j = 0; j < 2; j++) {
        acc[i][j] = __builtin_amdgcn_mfma_f32_16x16x32_bf16(ah[i], bh[j], acc[i][j], 0, 0, 0);
        acc[i][j] = __builtin_amdgcn_mfma_f32_16x16x32_bf16(ah[i], bl[j], acc[i][j], 0, 0, 0);
        acc[i][j] = __builtin_amdgcn_mfma_f32_16x16x32_bf16(al[i], bh[j], acc[i][j], 0, 0, 0);
      }
    __syncthreads();
  }

  // ---- epilogue (C/D: col = lane&15, row = quad*4 + r) ----
#pragma unroll
  for (int i = 0; i < 4; i++) {
#pragma unroll
    for (int j = 0; j < 2; j++) {
#pragma unroll
      for (int r = 0; r < 4; r++) {
        int row = bm + wm * 64 + i * 16 + quad * 4 + r;
        int col = bn + wn * 32 + j * 16 + ln;
        if (row < M && col < Nn) {
          float v = acc[i][j][r] + bias[col];
          if (EPI == 0) {
            v = v > 0.f ? v : 0.f;
            unsigned short h, l;
            split2(v, h, l);
            Ch[(size_t)row * ldc + col] = (short)h;
            Cl[(size_t)row * ldc + col] = (short)l;
          } else {
            float R = bfp2f(xp[(size_t)row * RD + tr + col]);
            xp[(size_t)row * RD + tw + col] = packsplit(R + 0.1f * v);
          }
        }
      }
    }
  }
}

// ---------------- fused final layer (200->1) + molecule segment-sum ----------
__global__ __launch_bounds__(256) void final_kernel(const short* __restrict__ hh,
                                                    const short* __restrict__ hl,
                                                    const float* __restrict__ w4,
                                                    const float* __restrict__ b4,
                                                    const int* __restrict__ mol,
                                                    float* __restrict__ out) {
  int node = blockIdx.x * 4 + (threadIdx.x >> 6);
  int lane = threadIdx.x & 63;
  if (node >= NN) return;
  float s = 0.f;
  for (int c = lane; c < HH; c += 64) {
    float v = ubf2f((unsigned short)hh[(size_t)node * HH + c]) +
              ubf2f((unsigned short)hl[(size_t)node * HH + c]);
    s += v * w4[c];
  }
  for (int off = 32; off > 0; off >>= 1) s += __shfl_down(s, off, 64);
  if (lane == 0) atomicAdd(&out[mol[node]], s + b4[0]);
}

// ---------------- host launcher ----------------
extern "C" void kernel_launch(void* const* d_in, const int* in_sizes, int n_in,
                              void* d_out, int out_size, void* d_ws, size_t ws_size,
                              hipStream_t stream) {
  const int* z_i = (const int*)d_in[0];
  const int* e_src = (const int*)d_in[1];
  const int* e_snk = ((const int*)d_in[1]) + EE;
  const float* dist = (const float*)d_in[2];
  const int* mol = (const int*)d_in[3];
  const float* emb = (const float*)d_in[4];
  const float* up_bn_g = (const float*)d_in[5];
  const float* up_bn_b = (const float*)d_in[6];
  const float* up_w1 = (const float*)d_in[7];
  const float* up_b1 = (const float*)d_in[8];
  const float* up_w2 = (const float*)d_in[9];
  const float* up_b2 = (const float*)d_in[10];
  const float* up_w3 = (const float*)d_in[11];
  const float* up_b3 = (const float*)d_in[12];
  const float* up_w4 = (const float*)d_in[13];
  const float* up_b4 = (const float*)d_in[14];
  const float* ro_bn_g = (const float*)d_in[15];
  const float* ro_bn_b = (const float*)d_in[16];
  const float* ro_w1 = (const float*)d_in[17];
  const float* ro_b1 = (const float*)d_in[18];
  const float* ro_w2 = (const float*)d_in[19];
  const float* ro_b2 = (const float*)d_in[20];
  const float* ro_w3 = (const float*)d_in[21];
  const float* ro_b3 = (const float*)d_in[22];
  const float* ro_w4 = (const float*)d_in[23];
  const float* ro_b4 = (const float*)d_in[24];
  float* out = (float*)d_out;

  char* p = (char*)d_ws;
  auto alloc = [&](size_t bytes) {
    void* r = (void*)p;
    p += (bytes + 255) & ~(size_t)255;
    return r;
  };
  unsigned* x_p = (unsigned*)alloc((size_t)NN * RD * 4);      // 51.2 MB
  short* h1h = (short*)alloc((size_t)NN * HH * 2);            // 20 MB
  short* h1l = (short*)alloc((size_t)NN * HH * 2);
  short* h2h = (short*)alloc((size_t)NN * HH * 2);            // m_h aliases front
  short* h2l = (short*)alloc((size_t)NN * HH * 2);            // m_l aliases front
  int* ssink = (int*)alloc((size_t)EE * 4);
  float* sdist = (float*)alloc((size_t)EE * 4);
  int* offs = (int*)alloc((size_t)(NN + 1) * 4);
  float* P = (float*)alloc((size_t)200 * 512 * 4);            // deg/cursor alias
  float* na = (float*)alloc(256 * 4);
  float* nb = (float*)alloc(256 * 4);
  // weight splits
  const int n_w1 = TT * MD * HH, n_w2 = TT * HH * HH, n_w3 = TT * HH * HH,
            n_w4 = TT * HH * ED, n_r1 = RD * HH, n_r2 = HH * HH, n_r3 = HH * HH;
  short* w1h = (short*)alloc((size_t)n_w1 * 2); short* w1l = (short*)alloc((size_t)n_w1 * 2);
  short* w2h = (short*)alloc((size_t)n_w2 * 2); short* w2l = (short*)alloc((size_t)n_w2 * 2);
  short* w3h = (short*)alloc((size_t)n_w3 * 2); short* w3l = (short*)alloc((size_t)n_w3 * 2);
  short* w4h = (short*)alloc((size_t)n_w4 * 2); short* w4l = (short*)alloc((size_t)n_w4 * 2);
  short* r1h = (short*)alloc((size_t)n_r1 * 2); short* r1l = (short*)alloc((size_t)n_r1 * 2);
  short* r2h = (short*)alloc((size_t)n_r2 * 2); short* r2l = (short*)alloc((size_t)n_r2 * 2);
  short* r3h = (short*)alloc((size_t)n_r3 * 2); short* r3l = (short*)alloc((size_t)n_r3 * 2);

  short* mh = h2h;  // [NN][96] aliases h2 pair (dead at gather time)
  short* ml = h2l;
  int* deg = (int*)P;         // alias: deg/cursor dead before P's first use
  int* cursor = deg + NN;

  hipMemsetAsync(deg, 0, (size_t)NN * 4, stream);
  hipMemsetAsync(out, 0, (size_t)NMOL * 4, stream);

  wsplit_kernel<<<(n_w1 + 255) / 256, 256, 0, stream>>>(up_w1, n_w1, w1h, w1l);
  wsplit_kernel<<<(n_w2 + 255) / 256, 256, 0, stream>>>(up_w2, n_w2, w2h, w2l);
  wsplit_kernel<<<(n_w3 + 255) / 256, 256, 0, stream>>>(up_w3, n_w3, w3h, w3l);
  wsplit_kernel<<<(n_w4 + 255) / 256, 256, 0, stream>>>(up_w4, n_w4, w4h, w4l);
  wsplit_kernel<<<(n_r1 + 255) / 256, 256, 0, stream>>>(ro_w1, n_r1, r1h, r1l);
  wsplit_kernel<<<(n_r2 + 255) / 256, 256, 0, stream>>>(ro_w2, n_r2, r2h, r2l);
  wsplit_kernel<<<(n_r3 + 255) / 256, 256, 0, stream>>>(ro_w3, n_r3, r3h, r3l);

  embsplit_kernel<<<(NN * ED + 255) / 256, 256, 0, stream>>>(z_i, emb, x_p);
  hist_kernel<<<(EE + 255) / 256, 256, 0, stream>>>(e_src, deg);
  scan_kernel<<<1, 1024, 0, stream>>>(deg, offs, cursor);
  scatter_kernel<<<(EE + 255) / 256, 256, 0, stream>>>(e_src, e_snk, dist, cursor, ssink, sdist);

  const int gM = (NN + 127) / 128;  // 391

  for (int t = 0; t < TT; t++) {
    gather_kernel<<<(NN + 3) / 4, 256, 0, stream>>>(offs, ssink, sdist, x_p, t * ED, mh, ml);
    colstats_pair_kernel<<<200, 256, 0, stream>>>(mh, ml, 96, MD, P);
    bnfinal_kernel<<<1, 256, 0, stream>>>(P, 200, up_bn_g + t * MD, up_bn_b + t * MD, MD, na, nb);
    bnsplit_m_kernel<<<(NN * 96 + 255) / 256, 256, 0, stream>>>(mh, ml, na, nb);

    // L1: m[87] -> h1[200]
    mgemm<0, false><<<dim3(gM, 4), 256, 0, stream>>>(
        mh, ml, nullptr, 96, w1h + t * MD * HH, w1l + t * MD * HH, HH, up_b1 + t * HH,
        nullptr, nullptr, nullptr, 0, 0, h1h, h1l, HH, NN, MD, 96, 96, HH);
    // L2: h1 -> h2
    mgemm<0, false><<<dim3(gM, 4), 256, 0, stream>>>(
        h1h, h1l, nullptr, HH, w2h + t * HH * HH, w2l + t * HH * HH, HH, up_b2 + t * HH,
        nullptr, nullptr, nullptr, 0, 0, h2h, h2l, HH, NN, HH, HH, 224, HH);
    // L3: h2 -> h1
    mgemm<0, false><<<dim3(gM, 4), 256, 0, stream>>>(
        h2h, h2l, nullptr, HH, w3h + t * HH * HH, w3l + t * HH * HH, HH, up_b3 + t * HH,
        nullptr, nullptr, nullptr, 0, 0, h1h, h1l, HH, NN, HH, HH, 224, HH);
    // L4: x[t+1] = x[t] + 0.1*(h1 @ W4 + b4)
    mgemm<1, false><<<dim3(gM, 1), 256, 0, stream>>>(
        h1h, h1l, nullptr, HH, w4h + t * HH * ED, w4l + t * HH * ED, ED, up_b4 + t * ED,
        nullptr, nullptr, x_p, t * ED, (t + 1) * ED, nullptr, nullptr, 0, NN, HH, HH, 224, ED);
  }

  // readout
  colstats_px_kernel<<<200, 256, 0, stream>>>(x_p, P);
  bnfinal_kernel<<<1, 256, 0, stream>>>(P, 200, ro_bn_g, ro_bn_b, RD, na, nb);
  mgemm<0, true><<<dim3(gM, 4), 256, 0, stream>>>(
      nullptr, nullptr, x_p, RD, r1h, r1l, HH, ro_b1, na, nb, nullptr, 0, 0,
      h1h, h1l, HH, NN, RD, RD, RD, HH);
  mgemm<0, false><<<dim3(gM, 4), 256, 0, stream>>>(
      h1h, h1l, nullptr, HH, r2h, r2l, HH, ro_b2, nullptr, nullptr, nullptr, 0, 0,
      h2h, h2l, HH, NN, HH, HH, 224, HH);
  mgemm<0, false><<<dim3(gM, 4), 256, 0, stream>>>(
      h2h, h2l, nullptr, HH, r3h, r3l, HH, ro_b3, nullptr, nullptr, nullptr, 0, 0,
      h1h, h1l, HH, NN, HH, HH, 224, HH);
  final_kernel<<<(NN + 3) / 4, 256, 0, stream>>>(h1h, h1l, ro_w4, ro_b4, mol, out);

  (void)in_sizes; (void)n_in; (void)out_size; (void)ws_size;
}

// Round 4
// 1553.963 us; speedup vs baseline: 1.7875x; 1.6020x over previous
//
#include <hip/hip_runtime.h>
#include <hip/hip_bf16.h>

#define NN 50000
#define EE 800000
#define TT 3
#define ED 64
#define NS 23
#define MD 87
#define HH 200
#define NMOL 2048
#define RD 256

#define BUF_S 228  // act buffer stride (u32): 228%32=4 -> 2-way banks (free)
#define AS_S 36    // streamed-A stride
#define LDS_WORDS (64 * BUF_S)  // 14592 u32 = 58368 B  (<= 64KB/WG limit!)

typedef __attribute__((ext_vector_type(8))) short short8b;
typedef __attribute__((ext_vector_type(4))) float f32x4;

// ---- bf16 split helpers: value = hi + lo, each bf16 (RNE). ----
__device__ __forceinline__ unsigned short f2bf(float f) {
  unsigned u = __float_as_uint(f);
  return (unsigned short)((u + 0x7fffu + ((u >> 16) & 1u)) >> 16);
}
__device__ __forceinline__ float ubf2f(unsigned short h) {
  return __uint_as_float(((unsigned)h) << 16);
}
// interleaved pair in one u32: low16 = hi-bf16, high16 = lo-bf16
__device__ __forceinline__ float bfp2f(unsigned p) {
  return __uint_as_float(p << 16) + __uint_as_float(p & 0xffff0000u);
}
__device__ __forceinline__ unsigned packsplit(float v) {
  unsigned short h = f2bf(v);
  unsigned short l = f2bf(v - ubf2f(h));
  return (unsigned)h | ((unsigned)l << 16);
}
// 8 packed u32 -> hi-frag + lo-frag (short8b each) via v_perm
__device__ __forceinline__ void unpack8(const unsigned* v, short8b& h, short8b& l) {
  union { unsigned u[4]; short8b s; } H, L;
#pragma unroll
  for (int e = 0; e < 4; e++) {
    H.u[e] = __builtin_amdgcn_perm(v[2 * e + 1], v[2 * e], 0x05040100u);
    L.u[e] = __builtin_amdgcn_perm(v[2 * e + 1], v[2 * e], 0x07060302u);
  }
  h = H.s;
  l = L.s;
}

// ---------------- weight prep: fp32 [T][K][N] -> u32-pair [T][Npad][Kpad] (transposed) ----
struct WD { const float* src; unsigned* dst; int K, N, Kpad, Npad, T; };
struct WDs { WD d[7]; };

__global__ __launch_bounds__(256) void wprep_kernel(WDs W) {
  WD w = W.d[blockIdx.y];
  int per = w.Npad * w.Kpad;
  int total = w.T * per;
  for (int idx = blockIdx.x * 256 + threadIdx.x; idx < total; idx += gridDim.x * 256) {
    int t = idx / per;
    int r = idx - t * per;
    int n = r / w.Kpad;
    int k = r - n * w.Kpad;
    unsigned v = 0;
    if (k < w.K && n < w.N) v = packsplit(w.src[((size_t)t * w.K + k) * w.N + n]);
    w.dst[idx] = v;
  }
}

// ---------------- embedding -> x slice 0 ----------------
__global__ __launch_bounds__(256) void emb_kernel(const int* __restrict__ z,
                                                  const float* __restrict__ emb,
                                                  unsigned* __restrict__ xp) {
  int idx = blockIdx.x * 256 + threadIdx.x;
  if (idx >= NN * ED) return;
  int i = idx >> 6, d = idx & 63;
  xp[(size_t)i * RD + d] = packsplit(emb[z[i] * ED + d]);
}

// ---------------- CSR build ----------------
__global__ __launch_bounds__(256) void hist_kernel(const int* __restrict__ src,
                                                   int* __restrict__ deg) {
  int e = blockIdx.x * 256 + threadIdx.x;
  if (e < EE) atomicAdd(&deg[src[e]], 1);
}

__global__ __launch_bounds__(1024) void scan_kernel(const int* __restrict__ deg,
                                                    int* __restrict__ offs,
                                                    int* __restrict__ cursor) {
  __shared__ int sh[1024];
  int tid = threadIdx.x;
  const int CH = (NN + 1023) / 1024;
  int s0 = tid * CH, s1 = s0 + CH;
  if (s1 > NN) s1 = NN;
  int sum = 0;
  for (int i = s0; i < s1; i++) sum += deg[i];
  sh[tid] = sum;
  __syncthreads();
  for (int off = 1; off < 1024; off <<= 1) {
    int t = (tid >= off) ? sh[tid - off] : 0;
    __syncthreads();
    sh[tid] += t;
    __syncthreads();
  }
  int base = sh[tid] - sum;
  for (int i = s0; i < s1; i++) {
    offs[i] = base;
    cursor[i] = base;
    base += deg[i];
  }
  if (tid == 1023) offs[NN] = sh[1023];
}

__global__ __launch_bounds__(256) void scatter_kernel(const int* __restrict__ src,
                                                      const int* __restrict__ snk,
                                                      const float* __restrict__ dist,
                                                      int* __restrict__ cursor,
                                                      int* __restrict__ ssink,
                                                      float* __restrict__ sdist) {
  int e = blockIdx.x * 256 + threadIdx.x;
  if (e >= EE) return;
  int p = atomicAdd(&cursor[src[e]], 1);
  ssink[p] = snk[e];
  sdist[p] = dist[e];
}

// ---------------- message gather: one wave per node ----------------
__global__ __launch_bounds__(256) void gather_kernel(const int* __restrict__ offs,
                                                     const int* __restrict__ ssink,
                                                     const float* __restrict__ sdist,
                                                     const unsigned* __restrict__ xp,
                                                     int toff, unsigned* __restrict__ m) {
  int node = blockIdx.x * 4 + (threadIdx.x >> 6);
  int lane = threadIdx.x & 63;
  if (node >= NN) return;
  float shift = (float)(0.8 + 0.1 * (double)lane);
  float accx = 0.f, accr = 0.f;
  int e0 = offs[node], e1 = offs[node + 1];
  for (int j = e0; j < e1; ++j) {
    int s = ssink[j];
    accx += bfp2f(xp[(size_t)s * RD + toff + lane]);
    if (lane < NS) {
      float u = sdist[j] - shift;
      accr += __expf(-u * u);
    }
  }
  if (lane < NS) m[node * 96 + lane] = packsplit(accr);
  m[node * 96 + NS + lane] = packsplit(accx);
}

// ---------------- batchnorm stats ----------------
template <int LD>
__global__ __launch_bounds__(256) void colstats_kernel(const unsigned* __restrict__ X,
                                                       int ncols, float* __restrict__ P) {
  int c = threadIdx.x;
  float s = 0.f, q = 0.f;
  if (c < ncols) {
    for (int r = blockIdx.x; r < NN; r += gridDim.x) {
      float v = bfp2f(X[(size_t)r * LD + c]);
      s += v;
      q += v * v;
    }
  }
  P[blockIdx.x * 512 + c] = s;
  P[blockIdx.x * 512 + 256 + c] = q;
}

__global__ __launch_bounds__(256) void bnfinal_kernel(const float* __restrict__ P, int nblk,
                                                      const float* __restrict__ g,
                                                      const float* __restrict__ b, int ncols,
                                                      float* __restrict__ na,
                                                      float* __restrict__ nb) {
  int c = threadIdx.x;
  float s = 0.f, q = 0.f;
  for (int i = 0; i < nblk; i++) {
    s += P[i * 512 + c];
    q += P[i * 512 + 256 + c];
  }
  if (c < ncols) {
    float mean = s / (float)NN;
    float var = q / (float)NN - mean * mean;
    float a = g[c] * rsqrtf(var + 1e-5f);
    na[c] = a;
    nb[c] = b[c] - mean * a;
  } else {
    na[c] = 0.f;  // zero-pad: BN at staging then zeroes pad columns automatically
    nb[c] = 0.f;
  }
}

// ---------------- fused MLP kernel ----------------
// 64-node tile per block; all layers with activations resident in LDS (pair format).
// B (weight) fragments read directly from global (L2-resident) -> no barriers in
// the K-loops of buf0-sourced layers. 4 waves split N: tiles {4,3,3,3} of 16.
// Split-precision: 3 MFMA (hh, hl, lh) per 16x16x32 tile -> fp32-equivalent.
template <bool READOUT>
__global__ __launch_bounds__(256, 2) void fused_kernel(
    const unsigned* __restrict__ Asrc, int astride,
    const float* __restrict__ na, const float* __restrict__ nb,
    const unsigned* __restrict__ W1t, const unsigned* __restrict__ W2t,
    const unsigned* __restrict__ W3t, const unsigned* __restrict__ W4t,
    const float* __restrict__ b1, const float* __restrict__ b2,
    const float* __restrict__ b3, const float* __restrict__ b4,
    unsigned* __restrict__ xp, int t,
    const float* __restrict__ w4ro, const int* __restrict__ mol,
    float* __restrict__ out) {
  __shared__ unsigned lds[LDS_WORDS];
  unsigned* buf0 = lds;      // 64 x BUF_S activation pair
  unsigned* As = lds;        // streamed-A double buffer 2 x 64 x AS_S = 4608 words, aliases buf0

  const int tid = threadIdx.x;
  const int wave = tid >> 6, lane = tid & 63, ln = lane & 15, quad = lane >> 4;
  const int bm = blockIdx.x * 64;

  const int ntile = (wave == 0) ? 4 : 3;
  const int n0col = (wave == 0) ? 0 : 16 + wave * 48;  // 0, 64, 112, 160

  f32x4 acc[4][4];

  auto run_layer = [&](const unsigned* __restrict__ Wt, int Kpad, int KP, bool streamA) {
#pragma unroll
    for (int i = 0; i < 4; i++)
#pragma unroll
      for (int j = 0; j < 4; j++) acc[i][j] = (f32x4){0.f, 0.f, 0.f, 0.f};

    int parity = 0;
    for (int k0 = 0; k0 < KP; k0 += 32, parity ^= 1) {
      if (streamA) {
        unsigned* Asb = As + parity * (64 * AS_S);
        int row = tid >> 2, seg = (tid & 3) * 8;
        int grow = bm + row;
        unsigned tmp[8];
        if (grow < NN) {
          const uint4* s = (const uint4*)(Asrc + (size_t)grow * astride + k0 + seg);
          *(uint4*)&tmp[0] = s[0];
          *(uint4*)&tmp[4] = s[1];
        } else {
#pragma unroll
          for (int e = 0; e < 8; e++) tmp[e] = 0;
        }
#pragma unroll
        for (int e = 0; e < 8; e++) {
          int k = k0 + seg + e;
          tmp[e] = packsplit(bfp2f(tmp[e]) * na[k] + nb[k]);
        }
        uint4* d = (uint4*)(Asb + row * AS_S + seg);
        d[0] = *(uint4*)&tmp[0];
        d[1] = *(uint4*)&tmp[4];
        __syncthreads();
      }
      // ---- A fragments (LDS) ----
      short8b ah[4], al[4];
#pragma unroll
      for (int i = 0; i < 4; i++) {
        int r = i * 16 + ln;
        const unsigned* ap = streamA ? (As + parity * (64 * AS_S) + r * AS_S + quad * 8)
                                     : (buf0 + r * BUF_S + k0 + quad * 8);
        unsigned v[8];
        *(uint4*)&v[0] = *(const uint4*)ap;
        *(uint4*)&v[4] = *(const uint4*)(ap + 4);
        unpack8(v, ah[i], al[i]);
      }
      // ---- B fragments (global, L2-hot) + MFMA ----
#pragma unroll
      for (int j = 0; j < 4; j++) {
        if (j < ntile) {
          int n = n0col + j * 16 + ln;
          const unsigned* bp = Wt + (size_t)n * Kpad + k0 + quad * 8;
          unsigned v[8];
          *(uint4*)&v[0] = *(const uint4*)bp;
          *(uint4*)&v[4] = *(const uint4*)(bp + 4);
          short8b bh, bl;
          unpack8(v, bh, bl);
#pragma unroll
          for (int i = 0; i < 4; i++) {
            acc[i][j] = __builtin_amdgcn_mfma_f32_16x16x32_bf16(ah[i], bh, acc[i][j], 0, 0, 0);
            acc[i][j] = __builtin_amdgcn_mfma_f32_16x16x32_bf16(ah[i], bl, acc[i][j], 0, 0, 0);
            acc[i][j] = __builtin_amdgcn_mfma_f32_16x16x32_bf16(al[i], bh, acc[i][j], 0, 0, 0);
          }
        }
      }
    }
  };

  // epilogue: relu(acc+bias) -> buf0; wave3 zero-fills pad cols [208,224)
  auto epi = [&](const float* __restrict__ bias) {
    __syncthreads();  // all frag reads of buf0/As complete before overwrite
#pragma unroll
    for (int i = 0; i < 4; i++)
#pragma unroll
      for (int j = 0; j < 4; j++) {
        if (j < ntile) {
#pragma unroll
          for (int r = 0; r < 4; r++) {
            int row = i * 16 + quad * 4 + r;
            int col = n0col + j * 16 + ln;
            float v = acc[i][j][r] + (col < HH ? bias[col] : 0.f);
            v = fmaxf(v, 0.f);
            buf0[row * BUF_S + col] = packsplit(v);
          }
        }
      }
    if (wave == 3) {
#pragma unroll
      for (int i = 0; i < 4; i++)
#pragma unroll
        for (int r = 0; r < 4; r++) {
          int row = i * 16 + quad * 4 + r;
          buf0[row * BUF_S + 208 + ln] = 0u;
        }
    }
    __syncthreads();
  };

  if (!READOUT) {
    run_layer(W1t, 96, 96, true);
    epi(b1);
    run_layer(W2t, 224, 224, false);
    epi(b2);
    run_layer(W3t, 224, 224, false);
    epi(b3);
    // ---- L4: each wave one 16-col tile of the 64 output cols ----
#pragma unroll
    for (int i = 0; i < 4; i++) acc[i][0] = (f32x4){0.f, 0.f, 0.f, 0.f};
    for (int k0 = 0; k0 < 224; k0 += 32) {
      short8b ah[4], al[4];
#pragma unroll
      for (int i = 0; i < 4; i++) {
        int r = i * 16 + ln;
        const unsigned* ap = buf0 + r * BUF_S + k0 + quad * 8;
        unsigned v[8];
        *(uint4*)&v[0] = *(const uint4*)ap;
        *(uint4*)&v[4] = *(const uint4*)(ap + 4);
        unpack8(v, ah[i], al[i]);
      }
      int n = wave * 16 + ln;
      const unsigned* bp = W4t + (size_t)n * 224 + k0 + quad * 8;
      unsigned v[8];
      *(uint4*)&v[0] = *(const uint4*)bp;
      *(uint4*)&v[4] = *(const uint4*)(bp + 4);
      short8b bh, bl;
      unpack8(v, bh, bl);
#pragma unroll
      for (int i = 0; i < 4; i++) {
        acc[i][0] = __builtin_amdgcn_mfma_f32_16x16x32_bf16(ah[i], bh, acc[i][0], 0, 0, 0);
        acc[i][0] = __builtin_amdgcn_mfma_f32_16x16x32_bf16(ah[i], bl, acc[i][0], 0, 0, 0);
        acc[i][0] = __builtin_amdgcn_mfma_f32_16x16x32_bf16(al[i], bh, acc[i][0], 0, 0, 0);
      }
    }
    // x-update epilogue: x[t+1] = x[t] + 0.1*(h3@W4 + b4)  (global only, no sync)
#pragma unroll
    for (int i = 0; i < 4; i++)
#pragma unroll
      for (int r = 0; r < 4; r++) {
        int grow = bm + i * 16 + quad * 4 + r;
        int col = wave * 16 + ln;
        if (grow < NN) {
          float v = acc[i][0][r] + b4[col];
          size_t base = (size_t)grow * RD;
          float old = bfp2f(xp[base + (size_t)t * ED + col]);
          xp[base + (size_t)(t + 1) * ED + col] = packsplit(old + 0.1f * v);
        }
      }
  } else {
    run_layer(W1t, 256, 256, true);
    epi(b1);
    run_layer(W2t, 224, 224, false);
    epi(b2);
    run_layer(W3t, 224, 224, false);
    epi(b3);
    // fused final layer (200->1) + molecule segment-sum
    int row = tid >> 2;
    int grow = bm + row;
    float s = 0.f;
    for (int c = (tid & 3); c < HH; c += 4) s += bfp2f(buf0[row * BUF_S + c]) * w4ro[c];
    s += __shfl_xor(s, 1, 64);
    s += __shfl_xor(s, 2, 64);
    if ((tid & 3) == 0 && grow < NN) atomicAdd(&out[mol[grow]], s + b4[0]);
  }
}

// ---------------- host launcher ----------------
extern "C" void kernel_launch(void* const* d_in, const int* in_sizes, int n_in,
                              void* d_out, int out_size, void* d_ws, size_t ws_size,
                              hipStream_t stream) {
  const int* z_i = (const int*)d_in[0];
  const int* e_src = (const int*)d_in[1];
  const int* e_snk = ((const int*)d_in[1]) + EE;
  const float* dist = (const float*)d_in[2];
  const int* mol = (const int*)d_in[3];
  const float* emb = (const float*)d_in[4];
  const float* up_bn_g = (const float*)d_in[5];
  const float* up_bn_b = (const float*)d_in[6];
  const float* up_w1 = (const float*)d_in[7];
  const float* up_b1 = (const float*)d_in[8];
  const float* up_w2 = (const float*)d_in[9];
  const float* up_b2 = (const float*)d_in[10];
  const float* up_w3 = (const float*)d_in[11];
  const float* up_b3 = (const float*)d_in[12];
  const float* up_w4 = (const float*)d_in[13];
  const float* up_b4 = (const float*)d_in[14];
  const float* ro_bn_g = (const float*)d_in[15];
  const float* ro_bn_b = (const float*)d_in[16];
  const float* ro_w1 = (const float*)d_in[17];
  const float* ro_b1 = (const float*)d_in[18];
  const float* ro_w2 = (const float*)d_in[19];
  const float* ro_b2 = (const float*)d_in[20];
  const float* ro_w3 = (const float*)d_in[21];
  const float* ro_b3 = (const float*)d_in[22];
  const float* ro_w4 = (const float*)d_in[23];
  const float* ro_b4 = (const float*)d_in[24];
  float* out = (float*)d_out;

  char* p = (char*)d_ws;
  auto alloc = [&](size_t bytes) {
    void* r = (void*)p;
    p += (bytes + 255) & ~(size_t)255;
    return r;
  };
  unsigned* x_p = (unsigned*)alloc((size_t)NN * RD * 4);   // 51.2 MB
  unsigned* m_p = (unsigned*)alloc((size_t)NN * 96 * 4);   // 19.2 MB
  int* ssink = (int*)alloc((size_t)EE * 4);
  float* sdist = (float*)alloc((size_t)EE * 4);
  int* offs = (int*)alloc((size_t)(NN + 1) * 4);
  int* deg = (int*)alloc((size_t)NN * 4);
  int* cursor = (int*)alloc((size_t)NN * 4);
  float* P = (float*)alloc((size_t)200 * 512 * 4);
  float* na = (float*)alloc(256 * 4);
  float* nb = (float*)alloc(256 * 4);
  // transposed/padded pair weights
  unsigned* w1t = (unsigned*)alloc((size_t)TT * 208 * 96 * 4);
  unsigned* w2t = (unsigned*)alloc((size_t)TT * 208 * 224 * 4);
  unsigned* w3t = (unsigned*)alloc((size_t)TT * 208 * 224 * 4);
  unsigned* w4t = (unsigned*)alloc((size_t)TT * 64 * 224 * 4);
  unsigned* r1t = (unsigned*)alloc((size_t)208 * 256 * 4);
  unsigned* r2t = (unsigned*)alloc((size_t)208 * 224 * 4);
  unsigned* r3t = (unsigned*)alloc((size_t)208 * 224 * 4);

  hipMemsetAsync(deg, 0, (size_t)NN * 4, stream);
  hipMemsetAsync(out, 0, (size_t)NMOL * 4, stream);

  WDs descs;
  descs.d[0] = {up_w1, w1t, MD, HH, 96, 208, TT};
  descs.d[1] = {up_w2, w2t, HH, HH, 224, 208, TT};
  descs.d[2] = {up_w3, w3t, HH, HH, 224, 208, TT};
  descs.d[3] = {up_w4, w4t, HH, ED, 224, 64, TT};
  descs.d[4] = {ro_w1, r1t, RD, HH, 256, 208, 1};
  descs.d[5] = {ro_w2, r2t, HH, HH, 224, 208, 1};
  descs.d[6] = {ro_w3, r3t, HH, HH, 224, 208, 1};
  wprep_kernel<<<dim3(273, 7), 256, 0, stream>>>(descs);

  emb_kernel<<<(NN * ED + 255) / 256, 256, 0, stream>>>(z_i, emb, x_p);
  hist_kernel<<<(EE + 255) / 256, 256, 0, stream>>>(e_src, deg);
  scan_kernel<<<1, 1024, 0, stream>>>(deg, offs, cursor);
  scatter_kernel<<<(EE + 255) / 256, 256, 0, stream>>>(e_src, e_snk, dist, cursor, ssink, sdist);

  const int gM = (NN + 63) / 64;  // 782

  for (int t = 0; t < TT; t++) {
    gather_kernel<<<(NN + 3) / 4, 256, 0, stream>>>(offs, ssink, sdist, x_p, t * ED, m_p);
    colstats_kernel<96><<<200, 256, 0, stream>>>(m_p, MD, P);
    bnfinal_kernel<<<1, 256, 0, stream>>>(P, 200, up_bn_g + t * MD, up_bn_b + t * MD, MD, na, nb);
    fused_kernel<false><<<gM, 256, 0, stream>>>(
        m_p, 96, na, nb,
        w1t + (size_t)t * 208 * 96, w2t + (size_t)t * 208 * 224,
        w3t + (size_t)t * 208 * 224, w4t + (size_t)t * 64 * 224,
        up_b1 + t * HH, up_b2 + t * HH, up_b3 + t * HH, up_b4 + t * ED,
        x_p, t, nullptr, nullptr, nullptr);
  }

  colstats_kernel<256><<<200, 256, 0, stream>>>(x_p, RD, P);
  bnfinal_kernel<<<1, 256, 0, stream>>>(P, 200, ro_bn_g, ro_bn_b, RD, na, nb);
  fused_kernel<true><<<gM, 256, 0, stream>>>(
      x_p, 256, na, nb,
      r1t, r2t, r3t, nullptr,
      ro_b1, ro_b2, ro_b3, ro_b4,
      nullptr, 0, ro_w4, mol, out);

  (void)in_sizes; (void)n_in; (void)out_size; (void)ws_size;
}